// Round 6
// baseline (1302.568 us; speedup 1.0000x reference)
//
#include <hip/hip_runtime.h>
#include <hip/hip_bf16.h>
#include <math.h>

#define IMG 224
#define TOK_IMG 50176
#define NTOK 200704

#define SXW_LD 264    // bf16 elems/row (256+8 pad) = 528 B
#define SQK_LD 520    // Q(256)|K(256) +8 pad = 1040 B ; also P overlay region
#define VT_LD  72     // V^T row (64 j + 8 pad) = 144 B

#define SCALE 0.17677669529663687f

typedef __attribute__((ext_vector_type(8))) short bf16x8;
typedef __attribute__((ext_vector_type(4))) float f32x4;

__device__ __forceinline__ float bf2f(ushort u){ return __uint_as_float(((unsigned)u)<<16); }
__device__ __forceinline__ ushort f2bf(float f){
  unsigned x = __float_as_uint(f);
  return (ushort)((x + 0x7fffu + ((x>>16)&1u)) >> 16);
}
__device__ __forceinline__ unsigned pk2(float a, float b){
  return (unsigned)f2bf(a) | ((unsigned)f2bf(b)<<16);
}
// exact-enough GELU: A&S 7.1.28 rational erf, |eps|<=3e-7 (h1 is bf16 anyway)
__device__ __forceinline__ float gelu(float v){
  float ax = fabsf(v)*0.70710678118654752f;
  float p = 1.f + ax*(0.0705230784f + ax*(0.0422820123f + ax*(0.0092705272f
          + ax*(0.0001520143f + ax*(0.0002765672f + ax*0.0000430638f)))));
  float p2 = p*p, p4 = p2*p2, p8 = p4*p4, p16 = p8*p8;
  float e = 1.f - __builtin_amdgcn_rcpf(p16);   // p16=inf -> e=1 (saturates)
  float er = copysignf(e, v);
  return 0.5f*v*(1.f + er);
}

// ---------------- weight transpose + fp32->bf16: dst[c*R+r] = bf16(src[r*C+c]) ----
__global__ __launch_bounds__(256) void transpose_f2b(const float* __restrict__ src,
                                                     ushort* __restrict__ dst, int R, int C){
  int idx = blockIdx.x*256 + threadIdx.x;
  if (idx >= R*C) return;
  int c = idx / R;
  int r = idx - c*R;
  dst[idx] = f2bf(src[r*C + c]);
}

// ---------------- fused LN1 + window attention (512 threads = 8 waves) ----------------
__global__ __launch_bounds__(512) void winattn_kernel(
    const float* __restrict__ x,
    const float* __restrict__ n1w, const float* __restrict__ n1b,
    const ushort* __restrict__ qkvT, const float* __restrict__ qkv_b,
    const ushort* __restrict__ projT, const float* __restrict__ proj_b,
    float* __restrict__ x2){
  __shared__ ushort sXw[64*SXW_LD];   // LN'd input tile; later attn-output tile
  __shared__ ushort sQK[64*SQK_LD];   // Q|K; later per-wave P slices
  __shared__ ushort sVt[256*VT_LD];   // V transposed [channel][token]

  int img = blockIdx.x >> 10;
  int wid = blockIdx.x & 1023;
  int wi  = wid >> 5, wj = wid & 31;
  int lane = threadIdx.x & 63, wvid = threadIdx.x >> 6;
  int l15 = lane & 15, lq = lane >> 4;

  // --- gather window tokens (with roll) + LayerNorm -> sXw bf16; rows 49..63 zero ---
  #pragma unroll 1
  for (int r = wvid; r < 64; r += 8){
    if (r < 49){
      int hg = wi*7 + (r/7) + 3; if (hg >= IMG) hg -= IMG;
      int wg = wj*7 + (r%7) + 3; if (wg >= IMG) wg -= IMG;
      size_t t = (size_t)img*TOK_IMG + (size_t)hg*IMG + wg;
      float4 u = *(const float4*)(x + t*256 + lane*4);
      float s  = u.x+u.y+u.z+u.w;
      float ss = u.x*u.x+u.y*u.y+u.z*u.z+u.w*u.w;
      #pragma unroll
      for (int off=32; off; off>>=1){ s += __shfl_xor(s,off); ss += __shfl_xor(ss,off); }
      float mean = s*(1.f/256.f);
      float var  = ss*(1.f/256.f) - mean*mean;
      float rstd = rsqrtf(var + 1e-5f);
      float4 wr = *(const float4*)(n1w + lane*4);
      float4 br = *(const float4*)(n1b + lane*4);
      uint2 p;
      p.x = pk2((u.x-mean)*rstd*wr.x+br.x, (u.y-mean)*rstd*wr.y+br.y);
      p.y = pk2((u.z-mean)*rstd*wr.z+br.z, (u.w-mean)*rstd*wr.w+br.w);
      *(uint2*)(sXw + r*SXW_LD + lane*4) = p;
    } else {
      *(uint2*)(sXw + r*SXW_LD + lane*4) = make_uint2(0u,0u);
    }
  }
  __syncthreads();

  // --- cache X A/B-fragments in registers (shared by QKV GEMM) ---
  bf16x8 bxw[4][8];
  #pragma unroll
  for (int mt=0;mt<4;++mt)
    #pragma unroll
    for (int kc=0;kc<8;++kc)
      bxw[mt][kc] = *(const bf16x8*)(sXw + (mt*16+l15)*SXW_LD + kc*32 + lq*8);

  // --- QKV GEMM: [64x256] @ [256x768]; Q (pre-scaled) | K -> sQK, V -> sVt transposed ---
  #pragma unroll 1
  for (int i = 0; i < 6; ++i){
    int nt = wvid + i*8;
    int n0 = nt*16;
    const ushort* bp = qkvT + (size_t)(n0+l15)*256 + lq*8;
    bf16x8 bfr[8];
    #pragma unroll
    for (int k=0;k<8;++k) bfr[k] = *(const bf16x8*)(bp + k*32);
    if (n0 < 512){
      // swapped operands: D[n-quad][m-lane] -> packed uint2 stores along n
      float4 b4 = *(const float4*)(qkv_b + n0 + lq*4);
      #pragma unroll
      for (int mt=0; mt<4; ++mt){
        f32x4 acc = {0.f,0.f,0.f,0.f};
        #pragma unroll
        for (int k=0;k<8;++k)
          acc = __builtin_amdgcn_mfma_f32_16x16x32_bf16(bfr[k], bxw[mt][k], acc, 0,0,0);
        int m = mt*16 + l15;
        uint2 t;
        if (n0 < 256){
          t.x = pk2((acc[0]+b4.x)*SCALE, (acc[1]+b4.y)*SCALE);
          t.y = pk2((acc[2]+b4.z)*SCALE, (acc[3]+b4.w)*SCALE);
        } else {
          t.x = pk2(acc[0]+b4.x, acc[1]+b4.y);
          t.y = pk2(acc[2]+b4.z, acc[3]+b4.w);
        }
        *(uint2*)(sQK + m*SQK_LD + n0 + lq*4) = t;
      }
    } else {
      // V: unswapped D[m-quad][c-lane]; pack along m into sVt rows
      float bias = qkv_b[n0 + l15];
      int c = n0 - 512 + l15;
      #pragma unroll
      for (int mt=0; mt<4; ++mt){
        f32x4 acc = {0.f,0.f,0.f,0.f};
        #pragma unroll
        for (int k=0;k<8;++k)
          acc = __builtin_amdgcn_mfma_f32_16x16x32_bf16(bxw[mt][k], bfr[k], acc, 0,0,0);
        uint2 t;
        t.x = pk2(acc[0]+bias, acc[1]+bias);
        t.y = pk2(acc[2]+bias, acc[3]+bias);
        *(uint2*)(sVt + c*VT_LD + mt*16 + lq*4) = t;
      }
    }
  }
  __syncthreads();

  // --- attention: wave wvid owns head wvid, all in MFMA ---
  {
    const unsigned long long REGMASK =
      (1ull<<32)|(1ull<<33)|(1ull<<34)|(1ull<<39)|(1ull<<40)|(1ull<<41)|
      (1ull<<46)|(1ull<<47)|(1ull<<48);
    int h = wvid;
    bool maskwin = (wid == 1023);

    bf16x8 aK[4], bQ[4];
    #pragma unroll
    for (int t=0;t<4;++t){
      aK[t] = *(const bf16x8*)(sQK + (t*16+l15)*SQK_LD + 256 + h*32 + lq*8);
      bQ[t] = *(const bf16x8*)(sQK + (t*16+l15)*SQK_LD +       h*32 + lq*8);
    }
    __syncthreads();   // Q|K consumed into regs by ALL waves; region reusable as P

    f32x4 st[4][4];
    const f32x4 z4 = {0.f,0.f,0.f,0.f};
    #pragma unroll
    for (int mj=0;mj<4;++mj)
      #pragma unroll
      for (int ni=0;ni<4;++ni)
        st[mj][ni] = __builtin_amdgcn_mfma_f32_16x16x32_bf16(aK[mj], bQ[ni], z4, 0,0,0);

    #pragma unroll
    for (int mj=0;mj<4;++mj){
      #pragma unroll
      for (int jj=0;jj<4;++jj){
        int j = mj*16 + lq*4 + jj;
        float pad = (j < 49) ? 0.f : -1e30f;
        unsigned rj = (unsigned)((REGMASK >> j) & 1ull);
        #pragma unroll
        for (int ni=0;ni<4;++ni){
          float mv = pad;
          if (maskwin){
            int i = ni*16 + l15;
            unsigned ri = (unsigned)((REGMASK >> i) & 1ull);
            if (ri != rj) mv -= 100.f;
          }
          st[mj][ni][jj] += mv;
        }
      }
    }

    #pragma unroll
    for (int ni=0;ni<4;++ni){
      float m = -1e30f;
      #pragma unroll
      for (int mj=0;mj<4;++mj)
        #pragma unroll
        for (int jj=0;jj<4;++jj) m = fmaxf(m, st[mj][ni][jj]);
      m = fmaxf(m, __shfl_xor(m,16));
      m = fmaxf(m, __shfl_xor(m,32));
      float s = 0.f;
      #pragma unroll
      for (int mj=0;mj<4;++mj)
        #pragma unroll
        for (int jj=0;jj<4;++jj){ float p = __expf(st[mj][ni][jj]-m); st[mj][ni][jj]=p; s += p; }
      s += __shfl_xor(s,16);
      s += __shfl_xor(s,32);
      float iv = 1.f / s;
      #pragma unroll
      for (int mj=0;mj<4;++mj)
        #pragma unroll
        for (int jj=0;jj<4;++jj) st[mj][ni][jj] *= iv;
    }

    // P (bf16, normalized) -> per-wave slice of dead Q|K region
    #pragma unroll
    for (int mj=0;mj<4;++mj){
      #pragma unroll
      for (int ni=0;ni<4;++ni){
        uint2 t;
        t.x = pk2(st[mj][ni][0], st[mj][ni][1]);
        t.y = pk2(st[mj][ni][2], st[mj][ni][3]);
        *(uint2*)(sQK + (ni*16+l15)*SQK_LD + wvid*64 + mj*16 + lq*4) = t;
      }
    }

    // O^T = V^T @ P^T
    f32x4 ot[2][4];
    #pragma unroll
    for (int md=0;md<2;++md)
      #pragma unroll
      for (int ni=0;ni<4;++ni) ot[md][ni] = z4;
    #pragma unroll
    for (int kc=0;kc<2;++kc){
      bf16x8 aV0 = *(const bf16x8*)(sVt + (h*32 +      l15)*VT_LD + kc*32 + lq*8);
      bf16x8 aV1 = *(const bf16x8*)(sVt + (h*32 + 16 + l15)*VT_LD + kc*32 + lq*8);
      #pragma unroll
      for (int ni=0;ni<4;++ni){
        bf16x8 bP = *(const bf16x8*)(sQK + (ni*16+l15)*SQK_LD + wvid*64 + kc*32 + lq*8);
        ot[0][ni] = __builtin_amdgcn_mfma_f32_16x16x32_bf16(aV0, bP, ot[0][ni], 0,0,0);
        ot[1][ni] = __builtin_amdgcn_mfma_f32_16x16x32_bf16(aV1, bP, ot[1][ni], 0,0,0);
      }
    }

    #pragma unroll
    for (int md=0;md<2;++md){
      #pragma unroll
      for (int ni=0;ni<4;++ni){
        uint2 t;
        t.x = pk2(ot[md][ni][0], ot[md][ni][1]);
        t.y = pk2(ot[md][ni][2], ot[md][ni][3]);
        *(uint2*)(sXw + (ni*16+l15)*SXW_LD + h*32 + md*16 + lq*4) = t;
      }
    }
  }
  __syncthreads();

  // --- proj GEMM [64x256]@[256x256] + shortcut(x) -> x2 fp32, float4 stores ---
  #pragma unroll 1
  for (int nn=0; nn<2; ++nn){
    int n0 = (wvid*2+nn)*16;
    const ushort* bp = projT + (size_t)(n0+l15)*256 + lq*8;
    bf16x8 wfr[8];
    #pragma unroll
    for (int k=0;k<8;++k) wfr[k] = *(const bf16x8*)(bp + k*32);
    float4 b4 = *(const float4*)(proj_b + n0 + lq*4);
    #pragma unroll
    for (int mt=0; mt<4; ++mt){
      f32x4 acc = {0.f,0.f,0.f,0.f};
      #pragma unroll
      for (int k=0;k<8;++k){
        bf16x8 af = *(const bf16x8*)(sXw + (mt*16+l15)*SXW_LD + k*32 + lq*8);
        acc = __builtin_amdgcn_mfma_f32_16x16x32_bf16(wfr[k], af, acc, 0,0,0);
      }
      int m = mt*16 + l15;
      if (m < 49){
        int hg = wi*7 + (m/7) + 3; if (hg >= IMG) hg -= IMG;
        int wg = wj*7 + (m%7) + 3; if (wg >= IMG) wg -= IMG;
        size_t t = (size_t)img*TOK_IMG + (size_t)hg*IMG + wg;
        float4 r = *(const float4*)(x + t*256 + n0 + lq*4);
        float4 o;
        o.x = acc[0] + b4.x + r.x;
        o.y = acc[1] + b4.y + r.y;
        o.z = acc[2] + b4.z + r.z;
        o.w = acc[3] + b4.w + r.w;
        *(float4*)(x2 + t*256 + n0 + lq*4) = o;
      }
    }
  }
}

// ---------------- fused MLP: M=32/block, 64 KiB LDS (sXn overlaid on sH1) -> 2 blk/CU ----
__global__ __launch_bounds__(512, 4) void mlp_kernel(
    const float* __restrict__ x2, const float* __restrict__ n2w, const float* __restrict__ n2b,
    const ushort* __restrict__ fc1T, const float* __restrict__ fc1b,
    const ushort* __restrict__ fc2T, const float* __restrict__ fc2b,
    float* __restrict__ out){
  __shared__ ushort sH1[32*1024];   // 64 KiB; first 16 KiB doubles as sXn
  ushort* sXn = sH1;
  int R0 = blockIdx.x * 32;
  int lane = threadIdx.x & 63, wvid = threadIdx.x >> 6;
  int l15 = lane & 15, lq = lane >> 4;

  // --- LN2 on 32 rows (4 per wave) -> sXn (swizzled) ---
  #pragma unroll 1
  for (int rr=0; rr<4; ++rr){
    int r = wvid*4 + rr;
    size_t tok = (size_t)R0 + r;
    float4 u = *(const float4*)(x2 + tok*256 + lane*4);
    float s  = u.x+u.y+u.z+u.w;
    float ss = u.x*u.x+u.y*u.y+u.z*u.z+u.w*u.w;
    #pragma unroll
    for (int off=32; off; off>>=1){ s += __shfl_xor(s,off); ss += __shfl_xor(ss,off); }
    float mean = s*(1.f/256.f);
    float var  = ss*(1.f/256.f) - mean*mean;
    float rstd = rsqrtf(var + 1e-5f);
    float4 wr = *(const float4*)(n2w + lane*4);
    float4 br = *(const float4*)(n2b + lane*4);
    uint2 p;
    p.x = pk2((u.x-mean)*rstd*wr.x+br.x, (u.y-mean)*rstd*wr.y+br.y);
    p.y = pk2((u.z-mean)*rstd*wr.z+br.z, (u.w-mean)*rstd*wr.w+br.w);
    int off8 = (r*512 + lane*8) ^ ((r&15)<<4);
    *(uint2*)((char*)sXn + off8) = p;
  }
  __syncthreads();

  // --- cache X fragments in registers: 2 row-blocks x 8 k-chunks (64 VGPR) ---
  bf16x8 bx[2][8];
  #pragma unroll
  for (int mt=0;mt<2;++mt){
    int m = mt*16 + l15;
    #pragma unroll
    for (int kc=0;kc<8;++kc){
      int off = (m*512 + kc*64 + lq*16) ^ ((m&15)<<4);
      bx[mt][kc] = *(const bf16x8*)((const char*)sXn + off);
    }
  }
  __syncthreads();   // sXn consumed by all waves; region now reusable as sH1

  // --- GEMM1 (swapped): D[n-quad][m-lane]; gelu; packed uint2 -> sH1 ---
  #pragma unroll 1
  for (int i=0;i<8;++i){
    int n0 = wvid*128 + i*16;
    const ushort* wp = fc1T + (size_t)(n0+l15)*256 + lq*8;
    bf16x8 w[8];
    #pragma unroll
    for (int kc=0;kc<8;++kc) w[kc] = *(const bf16x8*)(wp + kc*32);
    float4 b4 = *(const float4*)(fc1b + n0 + lq*4);
    f32x4 acc[2];
    #pragma unroll
    for (int mt=0;mt<2;++mt) acc[mt] = (f32x4){0.f,0.f,0.f,0.f};
    #pragma unroll
    for (int kc=0;kc<8;++kc)
      #pragma unroll
      for (int mt=0;mt<2;++mt)
        acc[mt] = __builtin_amdgcn_mfma_f32_16x16x32_bf16(w[kc], bx[mt][kc], acc[mt], 0,0,0);
    #pragma unroll
    for (int mt=0;mt<2;++mt){
      int m = mt*16 + l15;
      uint2 t;
      t.x = pk2(gelu(acc[mt][0]+b4.x), gelu(acc[mt][1]+b4.y));
      t.y = pk2(gelu(acc[mt][2]+b4.z), gelu(acc[mt][3]+b4.w));
      int off = (m*2048 + (n0+lq*4)*2) ^ ((m&15)<<4);
      *(uint2*)((char*)sH1 + off) = t;
    }
  }
  __syncthreads();

  // --- GEMM2 (swapped): 2 n-tiles/wave, 2 m-blocks; float4 out stores ---
  int n0a = wvid*32, n0b = n0a + 16;
  const ushort* wpa = fc2T + (size_t)(n0a+l15)*1024 + lq*8;
  const ushort* wpb = fc2T + (size_t)(n0b+l15)*1024 + lq*8;
  f32x4 acc2[2][2];
  #pragma unroll
  for (int s=0;s<2;++s)
    #pragma unroll
    for (int mb=0;mb<2;++mb) acc2[s][mb] = (f32x4){0.f,0.f,0.f,0.f};
  #pragma unroll 4
  for (int kc=0;kc<32;++kc){
    bf16x8 wa = *(const bf16x8*)(wpa + kc*32);
    bf16x8 wb = *(const bf16x8*)(wpb + kc*32);
    #pragma unroll
    for (int mb=0;mb<2;++mb){
      int m = mb*16 + l15;
      int off = (m*2048 + kc*64 + lq*16) ^ ((m&15)<<4);
      bf16x8 hb = *(const bf16x8*)((const char*)sH1 + off);
      acc2[0][mb] = __builtin_amdgcn_mfma_f32_16x16x32_bf16(wa, hb, acc2[0][mb], 0,0,0);
      acc2[1][mb] = __builtin_amdgcn_mfma_f32_16x16x32_bf16(wb, hb, acc2[1][mb], 0,0,0);
    }
  }
  float4 bA = *(const float4*)(fc2b + n0a + lq*4);
  float4 bB = *(const float4*)(fc2b + n0b + lq*4);
  #pragma unroll
  for (int mb=0;mb<2;++mb){
    size_t t = (size_t)R0 + mb*16 + l15;
    float4 rA = *(const float4*)(x2 + t*256 + n0a + lq*4);
    float4 oA;
    oA.x = acc2[0][mb][0] + bA.x + rA.x;
    oA.y = acc2[0][mb][1] + bA.y + rA.y;
    oA.z = acc2[0][mb][2] + bA.z + rA.z;
    oA.w = acc2[0][mb][3] + bA.w + rA.w;
    *(float4*)(out + t*256 + n0a + lq*4) = oA;
    float4 rB = *(const float4*)(x2 + t*256 + n0b + lq*4);
    float4 oB;
    oB.x = acc2[1][mb][0] + bB.x + rB.x;
    oB.y = acc2[1][mb][1] + bB.y + rB.y;
    oB.z = acc2[1][mb][2] + bB.z + rB.z;
    oB.w = acc2[1][mb][3] + bB.w + rB.w;
    *(float4*)(out + t*256 + n0b + lq*4) = oB;
  }
}

extern "C" void kernel_launch(void* const* d_in, const int* in_sizes, int n_in,
                              void* d_out, int out_size, void* d_ws, size_t ws_size,
                              hipStream_t stream) {
  const float* x      = (const float*)d_in[0];
  const float* qkv_w  = (const float*)d_in[3];
  const float* qkv_b  = (const float*)d_in[4];
  const float* proj_w = (const float*)d_in[5];
  const float* proj_b = (const float*)d_in[6];
  const float* n1w    = (const float*)d_in[7];
  const float* n1b    = (const float*)d_in[8];
  const float* n2w    = (const float*)d_in[9];
  const float* n2b    = (const float*)d_in[10];
  const float* fc1_w  = (const float*)d_in[11];
  const float* fc1_b  = (const float*)d_in[12];
  const float* fc2_w  = (const float*)d_in[13];
  const float* fc2_b  = (const float*)d_in[14];

  ushort* qkvT  = (ushort*)d_ws;                // 768 x 256 bf16
  ushort* projT = qkvT + 768*256;               // 256 x 256
  ushort* fc1T  = projT + 256*256;              // 1024 x 256
  ushort* fc2T  = fc1T + 1024*256;              // 256 x 1024
  float*  x2    = (float*)(fc2T + 256*1024);    // NTOK x 256 fp32
  size_t need = (size_t)(768*256 + 256*256 + 1024*256 + 256*1024)*2
              + (size_t)NTOK*256*4;
  if (ws_size < need) return;

  transpose_f2b<<<(768*256+255)/256, 256, 0, stream>>>(qkv_w, qkvT, 256, 768);
  transpose_f2b<<<(256*256+255)/256, 256, 0, stream>>>(proj_w, projT, 256, 256);
  transpose_f2b<<<(1024*256+255)/256, 256, 0, stream>>>(fc1_w, fc1T, 256, 1024);
  transpose_f2b<<<(256*1024+255)/256, 256, 0, stream>>>(fc2_w, fc2T, 1024, 256);

  winattn_kernel<<<4096, 512, 0, stream>>>(x, n1w, n1b, qkvT, qkv_b, projT, proj_b, x2);
  mlp_kernel<<<NTOK/32, 512, 0, stream>>>(x2, n2w, n2b, fc1T, fc1_b, fc2T, fc2_b,
                                          (float*)d_out);
}

// Round 7
// 1070.107 us; speedup vs baseline: 1.2172x; 1.2172x over previous
//
#include <hip/hip_runtime.h>
#include <hip/hip_bf16.h>
#include <math.h>

#define IMG 224
#define TOK_IMG 50176
#define NTOK 200704

#define SXW_LD 264    // bf16 elems/row (256+8 pad) = 528 B
#define SQK_LD 520    // Q(256)|K(256) +8 pad = 1040 B ; also P overlay region
#define VT_LD  72     // V^T row (64 j + 8 pad) = 144 B

#define SCALE 0.17677669529663687f

typedef __attribute__((ext_vector_type(8))) short bf16x8;
typedef __attribute__((ext_vector_type(4))) float f32x4;

__device__ __forceinline__ float bf2f(ushort u){ return __uint_as_float(((unsigned)u)<<16); }
__device__ __forceinline__ ushort f2bf(float f){
  unsigned x = __float_as_uint(f);
  return (ushort)((x + 0x7fffu + ((x>>16)&1u)) >> 16);
}
__device__ __forceinline__ unsigned pk2(float a, float b){
  return (unsigned)f2bf(a) | ((unsigned)f2bf(b)<<16);
}
// A&S 7.1.28 rational erf: |eps|<=3e-7 absolute (verified vs exact at v=-0.5)
__device__ __forceinline__ float gelu(float v){
  float ax = fabsf(v)*0.70710678118654752f;
  float p = 1.f + ax*(0.0705230784f + ax*(0.0422820123f + ax*(0.0092705272f
          + ax*(0.0001520143f + ax*(0.0002765672f + ax*0.0000430638f)))));
  float p2 = p*p, p4 = p2*p2, p8 = p4*p4, p16 = p8*p8;
  float e = 1.f - __builtin_amdgcn_rcpf(p16);   // p16=inf -> e=1 (saturates)
  float er = copysignf(e, v);
  return 0.5f*v*(1.f + er);
}

// ---------------- weight transpose + fp32->bf16: dst[c*R+r] = bf16(src[r*C+c]) ----
__global__ __launch_bounds__(256) void transpose_f2b(const float* __restrict__ src,
                                                     ushort* __restrict__ dst, int R, int C){
  int idx = blockIdx.x*256 + threadIdx.x;
  if (idx >= R*C) return;
  int c = idx / R;
  int r = idx - c*R;
  dst[idx] = f2bf(src[r*C + c]);
}

// ---------------- fused LN1 + window attention (512 threads = 8 waves) ----------------
__global__ __launch_bounds__(512) void winattn_kernel(
    const float* __restrict__ x,
    const float* __restrict__ n1w, const float* __restrict__ n1b,
    const ushort* __restrict__ qkvT, const float* __restrict__ qkv_b,
    const ushort* __restrict__ projT, const float* __restrict__ proj_b,
    float* __restrict__ x2){
  __shared__ ushort sXw[64*SXW_LD];   // LN'd input tile; later attn-output tile
  __shared__ ushort sQK[64*SQK_LD];   // Q|K; later per-wave P slices
  __shared__ ushort sVt[256*VT_LD];   // V transposed [channel][token]

  int img = blockIdx.x >> 10;
  int wid = blockIdx.x & 1023;
  int wi  = wid >> 5, wj = wid & 31;
  int lane = threadIdx.x & 63, wvid = threadIdx.x >> 6;
  int l15 = lane & 15, lq = lane >> 4;

  // --- gather window tokens (with roll) + LayerNorm -> sXw bf16; rows 49..63 zero ---
  #pragma unroll 1
  for (int r = wvid; r < 64; r += 8){
    if (r < 49){
      int hg = wi*7 + (r/7) + 3; if (hg >= IMG) hg -= IMG;
      int wg = wj*7 + (r%7) + 3; if (wg >= IMG) wg -= IMG;
      size_t t = (size_t)img*TOK_IMG + (size_t)hg*IMG + wg;
      float4 u = *(const float4*)(x + t*256 + lane*4);
      float s  = u.x+u.y+u.z+u.w;
      float ss = u.x*u.x+u.y*u.y+u.z*u.z+u.w*u.w;
      #pragma unroll
      for (int off=32; off; off>>=1){ s += __shfl_xor(s,off); ss += __shfl_xor(ss,off); }
      float mean = s*(1.f/256.f);
      float var  = ss*(1.f/256.f) - mean*mean;
      float rstd = rsqrtf(var + 1e-5f);
      float4 wr = *(const float4*)(n1w + lane*4);
      float4 br = *(const float4*)(n1b + lane*4);
      uint2 p;
      p.x = pk2((u.x-mean)*rstd*wr.x+br.x, (u.y-mean)*rstd*wr.y+br.y);
      p.y = pk2((u.z-mean)*rstd*wr.z+br.z, (u.w-mean)*rstd*wr.w+br.w);
      *(uint2*)(sXw + r*SXW_LD + lane*4) = p;
    } else {
      *(uint2*)(sXw + r*SXW_LD + lane*4) = make_uint2(0u,0u);
    }
  }
  __syncthreads();

  // --- cache X A/B-fragments in registers (shared by QKV GEMM) ---
  bf16x8 bxw[4][8];
  #pragma unroll
  for (int mt=0;mt<4;++mt)
    #pragma unroll
    for (int kc=0;kc<8;++kc)
      bxw[mt][kc] = *(const bf16x8*)(sXw + (mt*16+l15)*SXW_LD + kc*32 + lq*8);

  // --- QKV GEMM: [64x256] @ [256x768]; Q (pre-scaled) | K -> sQK, V -> sVt transposed ---
  #pragma unroll 1
  for (int i = 0; i < 6; ++i){
    int nt = wvid + i*8;
    int n0 = nt*16;
    const ushort* bp = qkvT + (size_t)(n0+l15)*256 + lq*8;
    bf16x8 bfr[8];
    #pragma unroll
    for (int k=0;k<8;++k) bfr[k] = *(const bf16x8*)(bp + k*32);
    if (n0 < 512){
      float4 b4 = *(const float4*)(qkv_b + n0 + lq*4);
      #pragma unroll
      for (int mt=0; mt<4; ++mt){
        f32x4 acc = {0.f,0.f,0.f,0.f};
        #pragma unroll
        for (int k=0;k<8;++k)
          acc = __builtin_amdgcn_mfma_f32_16x16x32_bf16(bfr[k], bxw[mt][k], acc, 0,0,0);
        int m = mt*16 + l15;
        uint2 t;
        if (n0 < 256){
          t.x = pk2((acc[0]+b4.x)*SCALE, (acc[1]+b4.y)*SCALE);
          t.y = pk2((acc[2]+b4.z)*SCALE, (acc[3]+b4.w)*SCALE);
        } else {
          t.x = pk2(acc[0]+b4.x, acc[1]+b4.y);
          t.y = pk2(acc[2]+b4.z, acc[3]+b4.w);
        }
        *(uint2*)(sQK + m*SQK_LD + n0 + lq*4) = t;
      }
    } else {
      float bias = qkv_b[n0 + l15];
      int c = n0 - 512 + l15;
      #pragma unroll
      for (int mt=0; mt<4; ++mt){
        f32x4 acc = {0.f,0.f,0.f,0.f};
        #pragma unroll
        for (int k=0;k<8;++k)
          acc = __builtin_amdgcn_mfma_f32_16x16x32_bf16(bxw[mt][k], bfr[k], acc, 0,0,0);
        uint2 t;
        t.x = pk2(acc[0]+bias, acc[1]+bias);
        t.y = pk2(acc[2]+bias, acc[3]+bias);
        *(uint2*)(sVt + c*VT_LD + mt*16 + lq*4) = t;
      }
    }
  }
  __syncthreads();

  // --- attention: wave wvid owns head wvid, all in MFMA ---
  {
    const unsigned long long REGMASK =
      (1ull<<32)|(1ull<<33)|(1ull<<34)|(1ull<<39)|(1ull<<40)|(1ull<<41)|
      (1ull<<46)|(1ull<<47)|(1ull<<48);
    int h = wvid;
    bool maskwin = (wid == 1023);

    bf16x8 aK[4], bQ[4];
    #pragma unroll
    for (int t=0;t<4;++t){
      aK[t] = *(const bf16x8*)(sQK + (t*16+l15)*SQK_LD + 256 + h*32 + lq*8);
      bQ[t] = *(const bf16x8*)(sQK + (t*16+l15)*SQK_LD +       h*32 + lq*8);
    }
    __syncthreads();   // Q|K consumed into regs by ALL waves; region reusable as P

    f32x4 st[4][4];
    const f32x4 z4 = {0.f,0.f,0.f,0.f};
    #pragma unroll
    for (int mj=0;mj<4;++mj)
      #pragma unroll
      for (int ni=0;ni<4;++ni)
        st[mj][ni] = __builtin_amdgcn_mfma_f32_16x16x32_bf16(aK[mj], bQ[ni], z4, 0,0,0);

    #pragma unroll
    for (int mj=0;mj<4;++mj){
      #pragma unroll
      for (int jj=0;jj<4;++jj){
        int j = mj*16 + lq*4 + jj;
        float pad = (j < 49) ? 0.f : -1e30f;
        unsigned rj = (unsigned)((REGMASK >> j) & 1ull);
        #pragma unroll
        for (int ni=0;ni<4;++ni){
          float mv = pad;
          if (maskwin){
            int i = ni*16 + l15;
            unsigned ri = (unsigned)((REGMASK >> i) & 1ull);
            if (ri != rj) mv -= 100.f;
          }
          st[mj][ni][jj] += mv;
        }
      }
    }

    #pragma unroll
    for (int ni=0;ni<4;++ni){
      float m = -1e30f;
      #pragma unroll
      for (int mj=0;mj<4;++mj)
        #pragma unroll
        for (int jj=0;jj<4;++jj) m = fmaxf(m, st[mj][ni][jj]);
      m = fmaxf(m, __shfl_xor(m,16));
      m = fmaxf(m, __shfl_xor(m,32));
      float s = 0.f;
      #pragma unroll
      for (int mj=0;mj<4;++mj)
        #pragma unroll
        for (int jj=0;jj<4;++jj){ float p = __expf(st[mj][ni][jj]-m); st[mj][ni][jj]=p; s += p; }
      s += __shfl_xor(s,16);
      s += __shfl_xor(s,32);
      float iv = 1.f / s;
      #pragma unroll
      for (int mj=0;mj<4;++mj)
        #pragma unroll
        for (int jj=0;jj<4;++jj) st[mj][ni][jj] *= iv;
    }

    // P (bf16, normalized) -> per-wave slice of dead Q|K region
    #pragma unroll
    for (int mj=0;mj<4;++mj){
      #pragma unroll
      for (int ni=0;ni<4;++ni){
        uint2 t;
        t.x = pk2(st[mj][ni][0], st[mj][ni][1]);
        t.y = pk2(st[mj][ni][2], st[mj][ni][3]);
        *(uint2*)(sQK + (ni*16+l15)*SQK_LD + wvid*64 + mj*16 + lq*4) = t;
      }
    }

    // O^T = V^T @ P^T
    f32x4 ot[2][4];
    #pragma unroll
    for (int md=0;md<2;++md)
      #pragma unroll
      for (int ni=0;ni<4;++ni) ot[md][ni] = z4;
    #pragma unroll
    for (int kc=0;kc<2;++kc){
      bf16x8 aV0 = *(const bf16x8*)(sVt + (h*32 +      l15)*VT_LD + kc*32 + lq*8);
      bf16x8 aV1 = *(const bf16x8*)(sVt + (h*32 + 16 + l15)*VT_LD + kc*32 + lq*8);
      #pragma unroll
      for (int ni=0;ni<4;++ni){
        bf16x8 bP = *(const bf16x8*)(sQK + (ni*16+l15)*SQK_LD + wvid*64 + kc*32 + lq*8);
        ot[0][ni] = __builtin_amdgcn_mfma_f32_16x16x32_bf16(aV0, bP, ot[0][ni], 0,0,0);
        ot[1][ni] = __builtin_amdgcn_mfma_f32_16x16x32_bf16(aV1, bP, ot[1][ni], 0,0,0);
      }
    }

    #pragma unroll
    for (int md=0;md<2;++md){
      #pragma unroll
      for (int ni=0;ni<4;++ni){
        uint2 t;
        t.x = pk2(ot[md][ni][0], ot[md][ni][1]);
        t.y = pk2(ot[md][ni][2], ot[md][ni][3]);
        *(uint2*)(sXw + (ni*16+l15)*SXW_LD + h*32 + md*16 + lq*4) = t;
      }
    }
  }
  __syncthreads();

  // --- proj GEMM [64x256]@[256x256] + shortcut(x) -> x2 fp32, float4 stores ---
  #pragma unroll 1
  for (int nn=0; nn<2; ++nn){
    int n0 = (wvid*2+nn)*16;
    const ushort* bp = projT + (size_t)(n0+l15)*256 + lq*8;
    bf16x8 wfr[8];
    #pragma unroll
    for (int k=0;k<8;++k) wfr[k] = *(const bf16x8*)(bp + k*32);
    float4 b4 = *(const float4*)(proj_b + n0 + lq*4);
    #pragma unroll
    for (int mt=0; mt<4; ++mt){
      f32x4 acc = {0.f,0.f,0.f,0.f};
      #pragma unroll
      for (int k=0;k<8;++k){
        bf16x8 af = *(const bf16x8*)(sXw + (mt*16+l15)*SXW_LD + k*32 + lq*8);
        acc = __builtin_amdgcn_mfma_f32_16x16x32_bf16(wfr[k], af, acc, 0,0,0);
      }
      int m = mt*16 + l15;
      if (m < 49){
        int hg = wi*7 + (m/7) + 3; if (hg >= IMG) hg -= IMG;
        int wg = wj*7 + (m%7) + 3; if (wg >= IMG) wg -= IMG;
        size_t t = (size_t)img*TOK_IMG + (size_t)hg*IMG + wg;
        float4 r = *(const float4*)(x + t*256 + n0 + lq*4);
        float4 o;
        o.x = acc[0] + b4.x + r.x;
        o.y = acc[1] + b4.y + r.y;
        o.z = acc[2] + b4.z + r.z;
        o.w = acc[3] + b4.w + r.w;
        *(float4*)(x2 + t*256 + n0 + lq*4) = o;
      }
    }
  }
}

// ---------------- fused MLP: M=64/block, K-streamed fc1->gelu->fc2, 64 KiB LDS ----
// Per chunk of 128 fc1-outputs: GEMM1 -> h1 chunk (16 KiB, double-buffered) ->
// partial GEMM2 accumulated in VGPRs. One barrier per chunk (dbuf-safe).
__global__ __launch_bounds__(512, 4) void mlp_kernel(
    const float* __restrict__ x2, const float* __restrict__ n2w, const float* __restrict__ n2b,
    const ushort* __restrict__ fc1T, const float* __restrict__ fc1b,
    const ushort* __restrict__ fc2T, const float* __restrict__ fc2b,
    float* __restrict__ out){
  __shared__ ushort sXn[64*256];      // 32 KiB, swizzle ((m&15)<<4)
  __shared__ ushort sH1[2][64*128];   // 2 x 16 KiB, swizzle ((m&7)<<4)
  int R0 = blockIdx.x * 64;
  int lane = threadIdx.x & 63, wvid = threadIdx.x >> 6;
  int l15 = lane & 15, lq = lane >> 4;

  // --- LN2 on 64 rows (8 per wave) -> sXn ---
  #pragma unroll 1
  for (int rr=0; rr<8; ++rr){
    int r = wvid*8 + rr;
    size_t tok = (size_t)R0 + r;
    float4 u = *(const float4*)(x2 + tok*256 + lane*4);
    float s  = u.x+u.y+u.z+u.w;
    float ss = u.x*u.x+u.y*u.y+u.z*u.z+u.w*u.w;
    #pragma unroll
    for (int off=32; off; off>>=1){ s += __shfl_xor(s,off); ss += __shfl_xor(ss,off); }
    float mean = s*(1.f/256.f);
    float var  = ss*(1.f/256.f) - mean*mean;
    float rstd = rsqrtf(var + 1e-5f);
    float4 wr = *(const float4*)(n2w + lane*4);
    float4 br = *(const float4*)(n2b + lane*4);
    uint2 p;
    p.x = pk2((u.x-mean)*rstd*wr.x+br.x, (u.y-mean)*rstd*wr.y+br.y);
    p.y = pk2((u.z-mean)*rstd*wr.z+br.z, (u.w-mean)*rstd*wr.w+br.w);
    int off8 = (r*512 + lane*8) ^ ((r&15)<<4);
    *(uint2*)((char*)sXn + off8) = p;
  }
  __syncthreads();

  f32x4 accO[4][2];
  #pragma unroll
  for (int mt=0;mt<4;++mt){ accO[mt][0]=(f32x4){0.f,0.f,0.f,0.f}; accO[mt][1]=(f32x4){0.f,0.f,0.f,0.f}; }
  int nO = wvid*32;   // this wave's fc2 output-column slice

  #pragma unroll 1
  for (int ch=0; ch<8; ++ch){
    ushort* hbuf = sH1[ch&1];
    // --- GEMM1: this wave's 16 fc1-outputs of the chunk ---
    int n1 = ch*128 + wvid*16;
    const ushort* w1p = fc1T + (size_t)(n1+l15)*256 + lq*8;
    bf16x8 w1[8];
    #pragma unroll
    for (int kc=0;kc<8;++kc) w1[kc] = *(const bf16x8*)(w1p + kc*32);
    f32x4 a1[4];
    #pragma unroll
    for (int mt=0;mt<4;++mt) a1[mt] = (f32x4){0.f,0.f,0.f,0.f};
    #pragma unroll
    for (int kc=0;kc<8;++kc){
      #pragma unroll
      for (int mt=0;mt<4;++mt){
        int m = mt*16 + l15;
        int off = (m*512 + kc*64 + lq*16) ^ ((m&15)<<4);
        bf16x8 xf = *(const bf16x8*)((const char*)sXn + off);
        a1[mt] = __builtin_amdgcn_mfma_f32_16x16x32_bf16(w1[kc], xf, a1[mt], 0,0,0);
      }
    }
    float4 b4 = *(const float4*)(fc1b + n1 + lq*4);
    #pragma unroll
    for (int mt=0;mt<4;++mt){
      int m = mt*16 + l15;
      uint2 t;
      t.x = pk2(gelu(a1[mt][0]+b4.x), gelu(a1[mt][1]+b4.y));
      t.y = pk2(gelu(a1[mt][2]+b4.z), gelu(a1[mt][3]+b4.w));
      int off = (m*256 + wvid*32 + lq*8) ^ ((m&7)<<4);
      *(uint2*)((char*)hbuf + off) = t;
    }
    __syncthreads();   // h1 chunk complete (writes to other buffer need no barrier)
    // --- GEMM2 partial: accumulate chunk's K=128 into accO ---
    const ushort* w2pa = fc2T + (size_t)(nO+l15)*1024 + ch*128 + lq*8;
    const ushort* w2pb = w2pa + (size_t)16*1024;
    #pragma unroll
    for (int kc=0;kc<4;++kc){
      bf16x8 w2a = *(const bf16x8*)(w2pa + kc*32);
      bf16x8 w2b = *(const bf16x8*)(w2pb + kc*32);
      #pragma unroll
      for (int mt=0;mt<4;++mt){
        int m = mt*16 + l15;
        int off = (m*256 + kc*64 + lq*16) ^ ((m&7)<<4);
        bf16x8 hf = *(const bf16x8*)((const char*)hbuf + off);
        accO[mt][0] = __builtin_amdgcn_mfma_f32_16x16x32_bf16(w2a, hf, accO[mt][0], 0,0,0);
        accO[mt][1] = __builtin_amdgcn_mfma_f32_16x16x32_bf16(w2b, hf, accO[mt][1], 0,0,0);
      }
    }
  }

  // --- epilogue: bias + residual + store ---
  float4 bA = *(const float4*)(fc2b + nO + lq*4);
  float4 bB = *(const float4*)(fc2b + nO + 16 + lq*4);
  #pragma unroll
  for (int mt=0;mt<4;++mt){
    size_t t = (size_t)R0 + mt*16 + l15;
    float4 rA = *(const float4*)(x2 + t*256 + nO + lq*4);
    float4 oA;
    oA.x = accO[mt][0][0] + bA.x + rA.x;
    oA.y = accO[mt][0][1] + bA.y + rA.y;
    oA.z = accO[mt][0][2] + bA.z + rA.z;
    oA.w = accO[mt][0][3] + bA.w + rA.w;
    *(float4*)(out + t*256 + nO + lq*4) = oA;
    float4 rB = *(const float4*)(x2 + t*256 + nO + 16 + lq*4);
    float4 oB;
    oB.x = accO[mt][1][0] + bB.x + rB.x;
    oB.y = accO[mt][1][1] + bB.y + rB.y;
    oB.z = accO[mt][1][2] + bB.z + rB.z;
    oB.w = accO[mt][1][3] + bB.w + rB.w;
    *(float4*)(out + t*256 + nO + 16 + lq*4) = oB;
  }
}

extern "C" void kernel_launch(void* const* d_in, const int* in_sizes, int n_in,
                              void* d_out, int out_size, void* d_ws, size_t ws_size,
                              hipStream_t stream) {
  const float* x      = (const float*)d_in[0];
  const float* qkv_w  = (const float*)d_in[3];
  const float* qkv_b  = (const float*)d_in[4];
  const float* proj_w = (const float*)d_in[5];
  const float* proj_b = (const float*)d_in[6];
  const float* n1w    = (const float*)d_in[7];
  const float* n1b    = (const float*)d_in[8];
  const float* n2w    = (const float*)d_in[9];
  const float* n2b    = (const float*)d_in[10];
  const float* fc1_w  = (const float*)d_in[11];
  const float* fc1_b  = (const float*)d_in[12];
  const float* fc2_w  = (const float*)d_in[13];
  const float* fc2_b  = (const float*)d_in[14];

  ushort* qkvT  = (ushort*)d_ws;                // 768 x 256 bf16
  ushort* projT = qkvT + 768*256;               // 256 x 256
  ushort* fc1T  = projT + 256*256;              // 1024 x 256
  ushort* fc2T  = fc1T + 1024*256;              // 256 x 1024
  float*  x2    = (float*)(fc2T + 256*1024);    // NTOK x 256 fp32
  size_t need = (size_t)(768*256 + 256*256 + 1024*256 + 256*1024)*2
              + (size_t)NTOK*256*4;
  if (ws_size < need) return;

  transpose_f2b<<<(768*256+255)/256, 256, 0, stream>>>(qkv_w, qkvT, 256, 768);
  transpose_f2b<<<(256*256+255)/256, 256, 0, stream>>>(proj_w, projT, 256, 256);
  transpose_f2b<<<(1024*256+255)/256, 256, 0, stream>>>(fc1_w, fc1T, 256, 1024);
  transpose_f2b<<<(256*1024+255)/256, 256, 0, stream>>>(fc2_w, fc2T, 1024, 256);

  winattn_kernel<<<4096, 512, 0, stream>>>(x, n1w, n1b, qkvT, qkv_b, projT, proj_b, x2);
  mlp_kernel<<<NTOK/64, 512, 0, stream>>>(x2, n2w, n2b, fc1T, fc1_b, fc2T, fc2_b,
                                          (float*)d_out);
}